// Round 8
// baseline (347.573 us; speedup 1.0000x reference)
//
#include <hip/hip_runtime.h>

typedef __bf16 bf16_t;
typedef __bf16 bf16x4 __attribute__((ext_vector_type(4)));
typedef __bf16 bf16x8 __attribute__((ext_vector_type(8)));
typedef float f32x4 __attribute__((ext_vector_type(4)));

#define NL 3
#define HD 128
#define ROWS 64
#define SSTR 128         // sigma(S)/s_r row stride: exactly 128 + XOR swizzle (T2) -> conflict-free
#define XSTR 24          // x(0..7) + [1,0..](8..15) + dead(16..23)
#define THREADS 512
#define BATCH 262144
#define NBLK (BATCH / ROWS)

// ws layout (bf16 elems): MFMA fragment order; biases folded at k==8; activation constants
// pre-multiplied into the weights: Sw,z,r x(-LOG2E); g x(+LOG2E) [gives 1-G]; h x(2*LOG2E).
#define SW_OFF 0                 // [ct=8][lane=64][j=8]                       = 4096
#define U_OFF  4096              // [l=3][g=4][ct=8][lane=64][j=8]             = 49152
#define W_OFF  53248             // [l=3][g=4][ct=8][kc=4][lane=64][j=8]       = 196608
#define WS_ELEMS 249856

#define MFMA(a, b, c) __builtin_amdgcn_mfma_f32_16x16x32_bf16((a), (b), (c), 0, 0, 0)

#define LOG2E 1.4426950408889634f
// activations on PRE-SCALED accumulators (no input multiply):
__device__ __forceinline__ float sige(float a) {   // = sigm(v) for a=-LOG2E*v ; = 1-sigm(v) for a=+LOG2E*v
    return __builtin_amdgcn_rcpf(1.f + __builtin_amdgcn_exp2f(a));
}
__device__ __forceinline__ float tanhe(float a) {  // = tanh(v) for a=2*LOG2E*v
    return 1.f - 2.f * __builtin_amdgcn_rcpf(__builtin_amdgcn_exp2f(a) + 1.f);
}
__device__ __forceinline__ float sigm(float v) {   // full sigmoid (for sigma(S_next))
    return __builtin_amdgcn_rcpf(1.f + __builtin_amdgcn_exp2f(-LOG2E * v));
}

// T2 XOR swizzle: 16-lane groups read different ROWS at the same col-slot; XOR the 8-elem
// slot index with (row&7) -> bank = slot^(row&7), a permutation in row -> conflict-free.
// Same mapping on write side (bijective within each row). col<128, accesses 8- or 4-aligned.
__device__ __forceinline__ int swz(int row, int col) {
    return row * SSTR + (((col >> 3) ^ (row & 7)) << 3) + (col & 7);
}

// ---------------- prep: swizzle f32 weights (+bias k==8, pre-scaled) into bf16 frag order ----
__global__ void dgm_prep(const float* __restrict__ SwW, const float* __restrict__ Swb,
                         const float* __restrict__ Uz, const float* __restrict__ Wz, const float* __restrict__ Bz,
                         const float* __restrict__ Ug, const float* __restrict__ Wg, const float* __restrict__ Bg,
                         const float* __restrict__ Ur, const float* __restrict__ Wr, const float* __restrict__ Br,
                         const float* __restrict__ Uh, const float* __restrict__ Wh,
                         bf16_t* __restrict__ ws) {
    int idx = blockIdx.x * 256 + threadIdx.x;
    if (idx >= WS_ELEMS) return;
    const float* Us[4] = {Uz, Ug, Ur, Uh};
    const float* Wm[4] = {Wz, Wg, Wr, Wh};
    const float gsc[4] = {-LOG2E, LOG2E, -LOG2E, 2.f * LOG2E};  // z, g, r, h
    if (idx < U_OFF) {
        int ct = idx >> 9, rem = idx & 511, lane = rem >> 3, j = rem & 7;
        int q = lane >> 4, mm = lane & 15;
        int k = q * 8 + j, n = ct * 16 + mm;
        float v = (k < 8) ? SwW[k * HD + n] : (k == 8) ? Swb[n] : 0.f;
        ws[idx] = (bf16_t)(v * -LOG2E);
    } else if (idx < W_OFF) {
        int t = idx - U_OFF;
        int lg = t >> 12, r2 = t & 4095;
        int l = lg >> 2, g = lg & 3;
        int ct = r2 >> 9, rem = r2 & 511, lane = rem >> 3, j = rem & 7;
        int q = lane >> 4, mm = lane & 15;
        int k = q * 8 + j, n = ct * 16 + mm;
        const float* Bs = (g == 0) ? Bz : (g == 1) ? Bg : (g == 2) ? Br : (const float*)0;
        float v = (k < 8) ? Us[g][(l * 8 + k) * HD + n]
                : (k == 8 && g < 3) ? Bs[l * HD + n] : 0.f;
        ws[idx] = (bf16_t)(v * gsc[g]);
    } else {
        int t = idx - W_OFF;
        int lg = t >> 14, r2 = t & 16383;
        int l = lg >> 2, g = lg & 3;
        int ct = r2 >> 11, kc = (r2 >> 9) & 3, rem = r2 & 511, lane = rem >> 3, j = rem & 7;
        int q = lane >> 4, mm = lane & 15;
        int k = kc * 32 + q * 8 + j, n = ct * 16 + mm;
        ws[idx] = (bf16_t)(Wm[g][(l * HD + k) * HD + n] * gsc[g]);
    }
}

// ---------------- main: r3 structure (206us best) + T2 XOR-swizzled s_sig/s_r ---------------
// Residency law (r1/r4/r5/r7): waves/SIMD = floor(256/VGPR), blocks quantize at 8 waves.
// VGPR<=64 -> 2 blocks/CU (43%) is the proven optimum; every push past it spilled or halved
// waves. This round changes ONE thing vs r3: SSTR 136->128 + XOR swizzle to kill the 2.4e7
// LDS bank-conflict cycles (~19% of kernel cycles). Canaries: VGPR<=64, WRITE_SIZE ~1MB.
__global__ __launch_bounds__(THREADS, 4) void dgm_main(
    const float* __restrict__ x,
    const float* __restrict__ Bh,
    const float* __restrict__ WfW, const float* __restrict__ WfB,
    const bf16_t* __restrict__ ws,
    float* __restrict__ out) {
    __shared__ __align__(16) bf16_t s_sig[ROWS * SSTR];  // sigma(S), single buffer, swizzled
    __shared__ __align__(16) bf16_t s_r[ROWS * SSTR];    // sigma(S)*R, swizzled
    __shared__ __align__(16) bf16_t s_xo[ROWS * XSTR];   // x | [1,0..] staging (linear)
    __shared__ float red[ROWS];

    const int tid = threadIdx.x;
    const int lane = tid & 63;
    const int ct = tid >> 6;
    const int m = lane & 15, q = lane >> 4;
    const int rb = blockIdx.x * ROWS;
    const int f0 = ct * 16 + q * 4;
    const int fragoff = (ct * 64 + lane) * 8;
    const int wfragoff = (ct * 4) * 512 + lane * 8;
    const int xoff = (q ? 8 : 0);   // q=0: x cols (k=0..7); q>=1: [1,0..] cols (k=8 hits bias row)

    if (tid < ROWS) red[tid] = 0.f;

    // stage x into s_xo cols 0..7 and [1,0,..,0] into cols 8..15
    {
        int r = tid >> 3, j = tid & 7;
        s_xo[r * XSTR + j] = (bf16_t)x[(size_t)(rb + r) * 8 + j];
        s_xo[r * XSTR + 8 + j] = (j == 0) ? (bf16_t)1.f : (bf16_t)0.f;
    }
    __syncthreads();

    bf16x4 svp[4];  // sigma(S) at this thread's 16 elements [bt]

    // ---- init: acc = -LOG2E*(x@Sw + b) ; sigma = sige(acc)
    {
        bf16x8 fSw = *(const bf16x8*)(ws + SW_OFF + fragoff);
#pragma unroll
        for (int bt = 0; bt < 4; bt++) {
            bf16x8 b = *(const bf16x8*)(&s_xo[(bt * 16 + m) * XSTR + xoff]);
            f32x4 acc = {0.f, 0.f, 0.f, 0.f};
            acc = MFMA(fSw, b, acc);
            bf16x4 pk;
#pragma unroll
            for (int i = 0; i < 4; i++) pk[i] = (bf16_t)sige(acc[i]);
            svp[bt] = pk;
            *(bf16x4*)(&s_sig[swz(bt * 16 + m, f0)]) = pk;
        }
    }
    __syncthreads();

#pragma unroll 1
    for (int l = 0; l < NL; l++) {
        const bool last = (l == NL - 1);
        const bf16_t* wb = ws + W_OFF + (size_t)l * 4 * 16384;
        const bf16_t* ub = ws + U_OFF + (size_t)l * 4 * 4096;

        // ---- P_A: R -> s_r  (Br folded, -LOG2E prescaled); reads s_sig, writes s_r.
        //      No barrier after: P_ZG also only READS s_sig; s_r not read until after barrier.
        {
            bf16x8 fU = *(const bf16x8*)(ub + 2 * 4096 + fragoff);
            bf16x8 fW[4];
#pragma unroll
            for (int kc = 0; kc < 4; kc++)
                fW[kc] = *(const bf16x8*)(wb + 2 * 16384 + wfragoff + kc * 512);
#pragma unroll
            for (int bt = 0; bt < 4; bt++) {
                const int row = bt * 16 + m;
                const bf16_t* xbase = &s_xo[row * XSTR];
                f32x4 aR = {0.f, 0.f, 0.f, 0.f};
#pragma unroll
                for (int kc = 0; kc < 4; kc++) {
                    bf16x8 b = *(const bf16x8*)(&s_sig[swz(row, kc * 32 + q * 8)]);
                    aR = MFMA(fW[kc], b, aR);
                }
                {
                    bf16x8 b = *(const bf16x8*)(xbase + xoff);   // x|1 chunk
                    aR = MFMA(fU, b, aR);
                }
                bf16x4 pk;
#pragma unroll
                for (int i = 0; i < 4; i++)
                    pk[i] = (bf16_t)(sige(aR[i]) * (float)svp[bt][i]);
                *(bf16x4*)(&s_r[swz(row, f0)]) = pk;
            }
        }

        bf16x4 t1p[4];  // z*sigma(S)
        bf16x4 ogp[4];  // 1-G

        // ---- P_ZG: Z and G share each B-fragment read (Bz/Bg folded; G prescaled +LOG2E -> sige gives 1-G)
        {
            bf16x8 fUz = *(const bf16x8*)(ub + 0 * 4096 + fragoff);
            bf16x8 fUg = *(const bf16x8*)(ub + 1 * 4096 + fragoff);
            bf16x8 fWz[4], fWg[4];
#pragma unroll
            for (int kc = 0; kc < 4; kc++) {
                fWz[kc] = *(const bf16x8*)(wb + 0 * 16384 + wfragoff + kc * 512);
                fWg[kc] = *(const bf16x8*)(wb + 1 * 16384 + wfragoff + kc * 512);
            }
#pragma unroll
            for (int bt = 0; bt < 4; bt++) {
                const int row = bt * 16 + m;
                const bf16_t* xbase = &s_xo[row * XSTR];
                f32x4 aZ = {0.f, 0.f, 0.f, 0.f}, aG = {0.f, 0.f, 0.f, 0.f};
#pragma unroll
                for (int kc = 0; kc < 4; kc++) {
                    bf16x8 b = *(const bf16x8*)(&s_sig[swz(row, kc * 32 + q * 8)]);
                    aZ = MFMA(fWz[kc], b, aZ);
                    aG = MFMA(fWg[kc], b, aG);
                }
                {
                    bf16x8 b = *(const bf16x8*)(xbase + xoff);   // x|1 chunk
                    aZ = MFMA(fUz, b, aZ);
                    aG = MFMA(fUg, b, aG);
                }
                bf16x4 t1, og;
#pragma unroll
                for (int i = 0; i < 4; i++) {
                    t1[i] = (bf16_t)(sige(aZ[i]) * (float)svp[bt][i]);
                    og[i] = (bf16_t)sige(aG[i]);
                }
                t1p[bt] = t1;
                ogp[bt] = og;
            }
        }
        __syncthreads();   // s_r visible to all; all s_sig reads complete before P_H overwrites

        // ---- P_H + state update (reads s_r + s_xo; Wh/Uh prescaled 2*LOG2E; bh scaled at load)
        //      writes new sigma(S) back into s_sig (single buffer; protected by barrier above)
        {
            bf16x8 fU = *(const bf16x8*)(ub + 3 * 4096 + fragoff);
            bf16x8 fW[4];
#pragma unroll
            for (int kc = 0; kc < 4; kc++)
                fW[kc] = *(const bf16x8*)(wb + 3 * 16384 + wfragoff + kc * 512);
            f32x4 bh4 = *(const f32x4*)&Bh[l * HD + f0];
#pragma unroll
            for (int i = 0; i < 4; i++) bh4[i] *= 2.f * LOG2E;
#pragma unroll
            for (int bt = 0; bt < 4; bt++) {
                const int row = bt * 16 + m;
                const bf16_t* xbase = &s_xo[row * XSTR];
                f32x4 aH = {0.f, 0.f, 0.f, 0.f};
#pragma unroll
                for (int kc = 0; kc < 4; kc++) {
                    bf16x8 b = *(const bf16x8*)(&s_r[swz(row, kc * 32 + q * 8)]);
                    aH = MFMA(fW[kc], b, aH);
                }
                {
                    bf16x8 b = *(const bf16x8*)(xbase);          // x chunk (Uh rows 8+ are 0)
                    aH = MFMA(fU, b, aH);
                }
                if (last) {
                    const f32x4 wf4 = *(const f32x4*)&WfW[f0];
                    float p = 0.f;
#pragma unroll
                    for (int i = 0; i < 4; i++) {
                        float hh = tanhe(aH[i] + bh4[i]);
                        float sn = (float)ogp[bt][i] * hh + (float)t1p[bt][i];
                        p += sn * wf4[i];              // fold S3@Wf; S3 stays f32
                    }
                    p += __shfl_xor(p, 16);            // sum over q (features)
                    p += __shfl_xor(p, 32);
                    if (q == 0) atomicAdd(&red[bt * 16 + m], p);
                } else {
                    bf16x4 pk;
#pragma unroll
                    for (int i = 0; i < 4; i++) {
                        float hh = tanhe(aH[i] + bh4[i]);
                        float sn = (float)ogp[bt][i] * hh + (float)t1p[bt][i];
                        pk[i] = (bf16_t)sigm(sn);
                    }
                    svp[bt] = pk;
                    *(bf16x4*)(&s_sig[swz(row, f0)]) = pk;
                }
            }
        }
        __syncthreads();   // s_sig(l+1) visible; all s_r reads done before next layer's P_A writes
    }

    if (tid < ROWS) out[rb + tid] = red[tid] + WfB[0];
}

extern "C" void kernel_launch(void* const* d_in, const int* in_sizes, int n_in,
                              void* d_out, int out_size, void* d_ws, size_t ws_size,
                              hipStream_t stream) {
    const float* x   = (const float*)d_in[0];
    const float* SwW = (const float*)d_in[1];
    const float* Swb = (const float*)d_in[2];
    const float* Uz  = (const float*)d_in[3];
    const float* Wz  = (const float*)d_in[4];
    const float* Bz  = (const float*)d_in[5];
    const float* Ug  = (const float*)d_in[6];
    const float* Wg  = (const float*)d_in[7];
    const float* Bg  = (const float*)d_in[8];
    const float* Ur  = (const float*)d_in[9];
    const float* Wr  = (const float*)d_in[10];
    const float* Br  = (const float*)d_in[11];
    const float* Uh  = (const float*)d_in[12];
    const float* Wh  = (const float*)d_in[13];
    const float* Bh  = (const float*)d_in[14];
    const float* WfW = (const float*)d_in[15];
    const float* WfB = (const float*)d_in[16];
    bf16_t* ws = (bf16_t*)d_ws;
    float* out = (float*)d_out;

    if (ws_size < (size_t)WS_ELEMS * sizeof(bf16_t)) return;

    dgm_prep<<<(WS_ELEMS + 255) / 256, 256, 0, stream>>>(SwW, Swb, Uz, Wz, Bz, Ug, Wg, Bg,
                                                         Ur, Wr, Br, Uh, Wh, ws);
    dgm_main<<<NBLK, THREADS, 0, stream>>>(x, Bh, WfW, WfB, ws, out);
}

// Round 10
// 259.753 us; speedup vs baseline: 1.3381x; 1.3381x over previous
//
#include <hip/hip_runtime.h>

typedef __bf16 bf16_t;
typedef __bf16 bf16x4 __attribute__((ext_vector_type(4)));
typedef __bf16 bf16x8 __attribute__((ext_vector_type(8)));
typedef float f32x4 __attribute__((ext_vector_type(4)));

#define NL 3
#define HD 128
#define ROWS 64
#define SSTR 136         // sigma(S): 128 data + 8 pad; 272B = 68 dw, mod 32 = 4 -> 2-way banks (free)
#define RSTR 136         // s_r (sigma(S)*R): same stride
#define XSTR 24          // x(0..7) + [1,0..](8..15) + dead(16..23)
#define THREADS 512
#define BATCH 262144
#define NBLK (BATCH / ROWS)

// ws layout (bf16 elems): MFMA fragment order; biases folded at k==8; activation constants
// pre-multiplied into the weights: Sw,z,r x(-LOG2E); g x(+LOG2E) [gives 1-G]; h x(2*LOG2E).
#define SW_OFF 0                 // [ct=8][lane=64][j=8]                       = 4096
#define U_OFF  4096              // [l=3][g=4][ct=8][lane=64][j=8]             = 49152
#define W_OFF  53248             // [l=3][g=4][ct=8][kc=4][lane=64][j=8]       = 196608
#define WS_ELEMS 249856

#define MFMA(a, b, c) __builtin_amdgcn_mfma_f32_16x16x32_bf16((a), (b), (c), 0, 0, 0)

#define LOG2E 1.4426950408889634f
// activations on PRE-SCALED accumulators (no input multiply):
__device__ __forceinline__ float sige(float a) {   // = sigm(v) for a=-LOG2E*v ; = 1-sigm(v) for a=+LOG2E*v
    return __builtin_amdgcn_rcpf(1.f + __builtin_amdgcn_exp2f(a));
}
__device__ __forceinline__ float tanhe(float a) {  // = tanh(v) for a=2*LOG2E*v
    return 1.f - 2.f * __builtin_amdgcn_rcpf(__builtin_amdgcn_exp2f(a) + 1.f);
}
__device__ __forceinline__ float sigm(float v) {   // full sigmoid (for sigma(S_next))
    return __builtin_amdgcn_rcpf(1.f + __builtin_amdgcn_exp2f(-LOG2E * v));
}

// ---------------- prep: swizzle f32 weights (+bias k==8, pre-scaled) into bf16 frag order ----
__global__ void dgm_prep(const float* __restrict__ SwW, const float* __restrict__ Swb,
                         const float* __restrict__ Uz, const float* __restrict__ Wz, const float* __restrict__ Bz,
                         const float* __restrict__ Ug, const float* __restrict__ Wg, const float* __restrict__ Bg,
                         const float* __restrict__ Ur, const float* __restrict__ Wr, const float* __restrict__ Br,
                         const float* __restrict__ Uh, const float* __restrict__ Wh,
                         bf16_t* __restrict__ ws) {
    int idx = blockIdx.x * 256 + threadIdx.x;
    if (idx >= WS_ELEMS) return;
    const float* Us[4] = {Uz, Ug, Ur, Uh};
    const float* Wm[4] = {Wz, Wg, Wr, Wh};
    const float gsc[4] = {-LOG2E, LOG2E, -LOG2E, 2.f * LOG2E};  // z, g, r, h
    if (idx < U_OFF) {
        int ct = idx >> 9, rem = idx & 511, lane = rem >> 3, j = rem & 7;
        int q = lane >> 4, mm = lane & 15;
        int k = q * 8 + j, n = ct * 16 + mm;
        float v = (k < 8) ? SwW[k * HD + n] : (k == 8) ? Swb[n] : 0.f;
        ws[idx] = (bf16_t)(v * -LOG2E);
    } else if (idx < W_OFF) {
        int t = idx - U_OFF;
        int lg = t >> 12, r2 = t & 4095;
        int l = lg >> 2, g = lg & 3;
        int ct = r2 >> 9, rem = r2 & 511, lane = rem >> 3, j = rem & 7;
        int q = lane >> 4, mm = lane & 15;
        int k = q * 8 + j, n = ct * 16 + mm;
        const float* Bs = (g == 0) ? Bz : (g == 1) ? Bg : (g == 2) ? Br : (const float*)0;
        float v = (k < 8) ? Us[g][(l * 8 + k) * HD + n]
                : (k == 8 && g < 3) ? Bs[l * HD + n] : 0.f;
        ws[idx] = (bf16_t)(v * gsc[g]);
    } else {
        int t = idx - W_OFF;
        int lg = t >> 14, r2 = t & 16383;
        int l = lg >> 2, g = lg & 3;
        int ct = r2 >> 11, kc = (r2 >> 9) & 3, rem = r2 & 511, lane = rem >> 3, j = rem & 7;
        int q = lane >> 4, mm = lane & 15;
        int k = kc * 32 + q * 8 + j, n = ct * 16 + mm;
        ws[idx] = (bf16_t)(Wm[g][(l * HD + k) * HD + n] * gsc[g]);
    }
}

// ---------------- main: r3 champion (205.6us) + T5 s_setprio around MFMA clusters -----------
// Ledger (r0-r8): occupancy register-pinned at 2 blocks/CU (VGPR law: waves/SIMD=floor(256/V),
// every escape spilled); barriers null; LDS volume null; bank swizzle null (counter structural)
// + spilled via broken imm-offset folding. This IS the r3 structure; only addition is setprio.
// Canaries: VGPR<=64, WRITE_SIZE ~1MB, FETCH ~6MB.
__global__ __launch_bounds__(THREADS, 4) void dgm_main(
    const float* __restrict__ x,
    const float* __restrict__ Bh,
    const float* __restrict__ WfW, const float* __restrict__ WfB,
    const bf16_t* __restrict__ ws,
    float* __restrict__ out) {
    __shared__ __align__(16) bf16_t s_sig[ROWS * SSTR];  // sigma(S), single buffer
    __shared__ __align__(16) bf16_t s_r[ROWS * RSTR];    // sigma(S)*R
    __shared__ __align__(16) bf16_t s_xo[ROWS * XSTR];   // x | [1,0..] staging
    __shared__ float red[ROWS];

    const int tid = threadIdx.x;
    const int lane = tid & 63;
    const int ct = tid >> 6;
    const int m = lane & 15, q = lane >> 4;
    const int rb = blockIdx.x * ROWS;
    const int f0 = ct * 16 + q * 4;
    const int fragoff = (ct * 64 + lane) * 8;
    const int wfragoff = (ct * 4) * 512 + lane * 8;
    const int xoff = (q ? 8 : 0);   // q=0: x cols (k=0..7); q>=1: [1,0..] cols (k=8 hits bias row)

    if (tid < ROWS) red[tid] = 0.f;

    // stage x into s_xo cols 0..7 and [1,0,..,0] into cols 8..15
    {
        int r = tid >> 3, j = tid & 7;
        s_xo[r * XSTR + j] = (bf16_t)x[(size_t)(rb + r) * 8 + j];
        s_xo[r * XSTR + 8 + j] = (j == 0) ? (bf16_t)1.f : (bf16_t)0.f;
    }
    __syncthreads();

    bf16x4 svp[4];  // sigma(S) at this thread's 16 elements [bt]

    // ---- init: acc = -LOG2E*(x@Sw + b) ; sigma = sige(acc)
    {
        bf16x8 fSw = *(const bf16x8*)(ws + SW_OFF + fragoff);
#pragma unroll
        for (int bt = 0; bt < 4; bt++) {
            bf16x8 b = *(const bf16x8*)(&s_xo[(bt * 16 + m) * XSTR + xoff]);
            f32x4 acc = {0.f, 0.f, 0.f, 0.f};
            acc = MFMA(fSw, b, acc);
            bf16x4 pk;
#pragma unroll
            for (int i = 0; i < 4; i++) pk[i] = (bf16_t)sige(acc[i]);
            svp[bt] = pk;
            *(bf16x4*)(&s_sig[(bt * 16 + m) * SSTR + f0]) = pk;
        }
    }
    __syncthreads();

#pragma unroll 1
    for (int l = 0; l < NL; l++) {
        const bool last = (l == NL - 1);
        const bf16_t* wb = ws + W_OFF + (size_t)l * 4 * 16384;
        const bf16_t* ub = ws + U_OFF + (size_t)l * 4 * 4096;

        // ---- P_A: R -> s_r  (Br folded, -LOG2E prescaled); reads s_sig, writes s_r.
        //      No barrier after: P_ZG also only READS s_sig; s_r not read until after barrier.
        {
            bf16x8 fU = *(const bf16x8*)(ub + 2 * 4096 + fragoff);
            bf16x8 fW[4];
#pragma unroll
            for (int kc = 0; kc < 4; kc++)
                fW[kc] = *(const bf16x8*)(wb + 2 * 16384 + wfragoff + kc * 512);
#pragma unroll
            for (int bt = 0; bt < 4; bt++) {
                const bf16_t* bbase = &s_sig[(bt * 16 + m) * SSTR];
                const bf16_t* xbase = &s_xo[(bt * 16 + m) * XSTR];
                f32x4 aR = {0.f, 0.f, 0.f, 0.f};
                __builtin_amdgcn_s_setprio(1);
#pragma unroll
                for (int kc = 0; kc < 4; kc++) {
                    bf16x8 b = *(const bf16x8*)(bbase + kc * 32 + q * 8);
                    aR = MFMA(fW[kc], b, aR);
                }
                {
                    bf16x8 b = *(const bf16x8*)(xbase + xoff);   // x|1 chunk
                    aR = MFMA(fU, b, aR);
                }
                __builtin_amdgcn_s_setprio(0);
                bf16x4 pk;
#pragma unroll
                for (int i = 0; i < 4; i++)
                    pk[i] = (bf16_t)(sige(aR[i]) * (float)svp[bt][i]);
                *(bf16x4*)(&s_r[(bt * 16 + m) * RSTR + f0]) = pk;
            }
        }

        bf16x4 t1p[4];  // z*sigma(S)
        bf16x4 ogp[4];  // 1-G

        // ---- P_ZG: Z and G share each B-fragment read (Bz/Bg folded; G prescaled +LOG2E -> sige gives 1-G)
        {
            bf16x8 fUz = *(const bf16x8*)(ub + 0 * 4096 + fragoff);
            bf16x8 fUg = *(const bf16x8*)(ub + 1 * 4096 + fragoff);
            bf16x8 fWz[4], fWg[4];
#pragma unroll
            for (int kc = 0; kc < 4; kc++) {
                fWz[kc] = *(const bf16x8*)(wb + 0 * 16384 + wfragoff + kc * 512);
                fWg[kc] = *(const bf16x8*)(wb + 1 * 16384 + wfragoff + kc * 512);
            }
#pragma unroll
            for (int bt = 0; bt < 4; bt++) {
                const bf16_t* bbase = &s_sig[(bt * 16 + m) * SSTR];
                const bf16_t* xbase = &s_xo[(bt * 16 + m) * XSTR];
                f32x4 aZ = {0.f, 0.f, 0.f, 0.f}, aG = {0.f, 0.f, 0.f, 0.f};
                __builtin_amdgcn_s_setprio(1);
#pragma unroll
                for (int kc = 0; kc < 4; kc++) {
                    bf16x8 b = *(const bf16x8*)(bbase + kc * 32 + q * 8);
                    aZ = MFMA(fWz[kc], b, aZ);
                    aG = MFMA(fWg[kc], b, aG);
                }
                {
                    bf16x8 b = *(const bf16x8*)(xbase + xoff);   // x|1 chunk
                    aZ = MFMA(fUz, b, aZ);
                    aG = MFMA(fUg, b, aG);
                }
                __builtin_amdgcn_s_setprio(0);
                bf16x4 t1, og;
#pragma unroll
                for (int i = 0; i < 4; i++) {
                    t1[i] = (bf16_t)(sige(aZ[i]) * (float)svp[bt][i]);
                    og[i] = (bf16_t)sige(aG[i]);
                }
                t1p[bt] = t1;
                ogp[bt] = og;
            }
        }
        __syncthreads();   // s_r visible to all; all s_sig reads complete before P_H overwrites

        // ---- P_H + state update (reads s_r + s_xo; Wh/Uh prescaled 2*LOG2E; bh scaled at load)
        //      writes new sigma(S) back into s_sig (single buffer; protected by barrier above)
        {
            bf16x8 fU = *(const bf16x8*)(ub + 3 * 4096 + fragoff);
            bf16x8 fW[4];
#pragma unroll
            for (int kc = 0; kc < 4; kc++)
                fW[kc] = *(const bf16x8*)(wb + 3 * 16384 + wfragoff + kc * 512);
            f32x4 bh4 = *(const f32x4*)&Bh[l * HD + f0];
#pragma unroll
            for (int i = 0; i < 4; i++) bh4[i] *= 2.f * LOG2E;
#pragma unroll
            for (int bt = 0; bt < 4; bt++) {
                const bf16_t* bbase = &s_r[(bt * 16 + m) * RSTR];
                const bf16_t* xbase = &s_xo[(bt * 16 + m) * XSTR];
                f32x4 aH = {0.f, 0.f, 0.f, 0.f};
                __builtin_amdgcn_s_setprio(1);
#pragma unroll
                for (int kc = 0; kc < 4; kc++) {
                    bf16x8 b = *(const bf16x8*)(bbase + kc * 32 + q * 8);
                    aH = MFMA(fW[kc], b, aH);
                }
                {
                    bf16x8 b = *(const bf16x8*)(xbase);          // x chunk (Uh rows 8+ are 0)
                    aH = MFMA(fU, b, aH);
                }
                __builtin_amdgcn_s_setprio(0);
                if (last) {
                    const f32x4 wf4 = *(const f32x4*)&WfW[f0];
                    float p = 0.f;
#pragma unroll
                    for (int i = 0; i < 4; i++) {
                        float hh = tanhe(aH[i] + bh4[i]);
                        float sn = (float)ogp[bt][i] * hh + (float)t1p[bt][i];
                        p += sn * wf4[i];              // fold S3@Wf; S3 stays f32
                    }
                    p += __shfl_xor(p, 16);            // sum over q (features)
                    p += __shfl_xor(p, 32);
                    if (q == 0) atomicAdd(&red[bt * 16 + m], p);
                } else {
                    bf16x4 pk;
#pragma unroll
                    for (int i = 0; i < 4; i++) {
                        float hh = tanhe(aH[i] + bh4[i]);
                        float sn = (float)ogp[bt][i] * hh + (float)t1p[bt][i];
                        pk[i] = (bf16_t)sigm(sn);
                    }
                    svp[bt] = pk;
                    *(bf16x4*)(&s_sig[(bt * 16 + m) * SSTR + f0]) = pk;
                }
            }
        }
        __syncthreads();   // s_sig(l+1) visible; all s_r reads done before next layer's P_A writes
    }

    if (tid < ROWS) out[rb + tid] = red[tid] + WfB[0];
}

extern "C" void kernel_launch(void* const* d_in, const int* in_sizes, int n_in,
                              void* d_out, int out_size, void* d_ws, size_t ws_size,
                              hipStream_t stream) {
    const float* x   = (const float*)d_in[0];
    const float* SwW = (const float*)d_in[1];
    const float* Swb = (const float*)d_in[2];
    const float* Uz  = (const float*)d_in[3];
    const float* Wz  = (const float*)d_in[4];
    const float* Bz  = (const float*)d_in[5];
    const float* Ug  = (const float*)d_in[6];
    const float* Wg  = (const float*)d_in[7];
    const float* Bg  = (const float*)d_in[8];
    const float* Ur  = (const float*)d_in[9];
    const float* Wr  = (const float*)d_in[10];
    const float* Br  = (const float*)d_in[11];
    const float* Uh  = (const float*)d_in[12];
    const float* Wh  = (const float*)d_in[13];
    const float* Bh  = (const float*)d_in[14];
    const float* WfW = (const float*)d_in[15];
    const float* WfB = (const float*)d_in[16];
    bf16_t* ws = (bf16_t*)d_ws;
    float* out = (float*)d_out;

    if (ws_size < (size_t)WS_ELEMS * sizeof(bf16_t)) return;

    dgm_prep<<<(WS_ELEMS + 255) / 256, 256, 0, stream>>>(SwW, Swb, Uz, Wz, Bz, Ug, Wg, Bg,
                                                         Ur, Wr, Br, Uh, Wh, ws);
    dgm_main<<<NBLK, THREADS, 0, stream>>>(x, Bh, WfW, WfB, ws, out);
}